// Round 10
// baseline (266.143 us; speedup 1.0000x reference)
//
#include <hip/hip_runtime.h>
#include <math.h>

#define NB   16
#define NBEF 512
#define NSTK 256
#define CCO  128
#define SPIN 512
#define SPOUT 256
#define DNIN 128
#define DNOUT 128
#define NPNT 32
#define SP_ELEMS (NB * SPOUT * NBEF)   // 2,097,152 f32 elems (sparse output)

typedef __attribute__((ext_vector_type(8))) short bf16x8v;   // 8 bf16 = 4 VGPR
typedef __attribute__((ext_vector_type(4))) float f32x4v;    // MFMA C/D

typedef __attribute__((address_space(1))) const unsigned int* gas1_t;
typedef __attribute__((address_space(3))) unsigned int* las3_t;

__device__ __forceinline__ unsigned short f32_to_bf16(float f) {
    unsigned int u = __float_as_uint(f);
    u += 0x7fffu + ((u >> 16) & 1u);     // round-to-nearest-even
    return (unsigned short)(u >> 16);
}

// gelu(tanh approx) with hw exp2: tanh(z)=sign(z)*(1-2/(2^(2|z|*log2e)+1))
__device__ __forceinline__ float fast_gelu(float x) {
    float z = 0.7978845608028654f * x * (1.0f + 0.044715f * x * x);
    float az = fabsf(z) * 2.885390081777927f;   // 2*log2(e)
    float e;
    asm("v_exp_f32 %0, %1" : "=v"(e) : "v"(az));
    float r = __builtin_amdgcn_rcpf(e + 1.0f);
    float th = copysignf(1.0f - 2.0f * r, z);
    return 0.5f * x * (1.0f + th);
}

// order-preserving float -> uint map
__device__ __forceinline__ unsigned int f2ord(float f) {
    unsigned int u = __float_as_uint(f);
    return (u & 0x80000000u) ? ~u : (u | 0x80000000u);
}
__device__ __forceinline__ float ord2f(unsigned int o) {
    unsigned int u = (o & 0x80000000u) ? (o & 0x7fffffffu) : ~o;
    return __uint_as_float(u);
}

__device__ __forceinline__ unsigned long long wave_min_u64(unsigned long long k) {
    #pragma unroll
    for (int d = 32; d >= 1; d >>= 1) {
        unsigned long long o = __shfl_xor(k, d, 64);
        if (o < k) k = o;
    }
    return k;
}

// ---------------- Kernel 0: tiled 2-NN (GEMM-style staging, wave-local top-2) ----------------
__global__ __launch_bounds__(256) void knn_kernel(
    const float* __restrict__ stk_coor,      // [B][256][128]
    const float* __restrict__ stk_coor_bef,  // [B][512][128]
    int2* __restrict__ idx_out,              // [B][512]
    float2* __restrict__ w_out)              // [B][512]
{
    int b  = blockIdx.y;
    int q0 = blockIdx.x * 16;
    int tid  = threadIdx.x;
    int lane = tid & 63;
    int qg   = tid >> 6;                     // wave id: queries qg*4..+4
    int pg   = lane;                         // points pg*4..+4

    __shared__ float Qt[128][16];            // [c][q] 8 KB
    __shared__ float Pt[32][260];            // [c-chunk][p] 33.3 KB (pad 4)

    {
        int q = tid >> 4, c0 = (tid & 15) * 8;
        const float* src = stk_coor_bef + ((size_t)b * NBEF + q0 + q) * CCO + c0;
        float4 v0 = *reinterpret_cast<const float4*>(src);
        float4 v1 = *reinterpret_cast<const float4*>(src + 4);
        Qt[c0+0][q] = v0.x; Qt[c0+1][q] = v0.y; Qt[c0+2][q] = v0.z; Qt[c0+3][q] = v0.w;
        Qt[c0+4][q] = v1.x; Qt[c0+5][q] = v1.y; Qt[c0+6][q] = v1.z; Qt[c0+7][q] = v1.w;
    }

    float dot[4][4];
    #pragma unroll
    for (int a = 0; a < 4; ++a)
        #pragma unroll
        for (int c = 0; c < 4; ++c) dot[a][c] = 0.f;
    float qn[4] = {0.f, 0.f, 0.f, 0.f};
    float pn[4] = {0.f, 0.f, 0.f, 0.f};

    for (int ct = 0; ct < 4; ++ct) {
        __syncthreads();
        #pragma unroll
        for (int it = 0; it < 8; ++it) {
            int p  = (tid >> 3) + it * 32;
            int cl = (tid & 7) * 4;
            float4 v = *reinterpret_cast<const float4*>(
                stk_coor + ((size_t)b * NSTK + p) * CCO + ct * 32 + cl);
            Pt[cl+0][p] = v.x; Pt[cl+1][p] = v.y; Pt[cl+2][p] = v.z; Pt[cl+3][p] = v.w;
        }
        __syncthreads();
        #pragma unroll 8
        for (int c = 0; c < 32; ++c) {
            float4 qv = *reinterpret_cast<const float4*>(&Qt[ct*32 + c][qg*4]);
            float4 pv = *reinterpret_cast<const float4*>(&Pt[c][pg*4]);
            float qa[4] = {qv.x, qv.y, qv.z, qv.w};
            float pa[4] = {pv.x, pv.y, pv.z, pv.w};
            #pragma unroll
            for (int j = 0; j < 4; ++j) {
                qn[j] += qa[j] * qa[j];
                pn[j] += pa[j] * pa[j];
                #pragma unroll
                for (int k = 0; k < 4; ++k) dot[j][k] += qa[j] * pa[k];
            }
        }
    }

    #pragma unroll
    for (int qj = 0; qj < 4; ++qj) {
        unsigned long long kA = 0xFFFFFFFFFFFFFFFFull, kB = 0xFFFFFFFFFFFFFFFFull;
        #pragma unroll
        for (int pj = 0; pj < 4; ++pj) {
            float d2 = qn[qj] + pn[pj] - 2.f * dot[qj][pj];
            unsigned long long key =
                ((unsigned long long)f2ord(d2) << 32) | (unsigned int)(pg * 4 + pj);
            if (key < kA)      { kB = kA; kA = key; }
            else if (key < kB) { kB = key; }
        }
        unsigned long long m0 = wave_min_u64(kA);
        unsigned long long c2 = (kA == m0) ? kB : kA;
        unsigned long long m1 = wave_min_u64(c2);
        if (lane == 0) {
            float d0 = ord2f((unsigned int)(m0 >> 32));
            float d1 = ord2f((unsigned int)(m1 >> 32));
            int j0 = (int)(m0 & 0xffffffffu), j1 = (int)(m1 & 0xffffffffu);
            float r0 = 1.f / (d0 + 1e-8f);
            float r1 = 1.f / (d1 + 1e-8f);
            float s = r0 + r1;
            int q = q0 + qg * 4 + qj;
            idx_out[b * NBEF + q] = make_int2(j0, j1);
            w_out[b * NBEF + q]   = make_float2(r0 / s, r1 / s);
        }
    }
}

// ---------------- Kernel 1: one-time A-matrix -> MFMA-fragment-linear bf16 ----------------
__global__ __launch_bounds__(256) void prep_a_kernel(
    const float* __restrict__ w_ct,          // [128][128][4]
    unsigned short* __restrict__ Aws)        // 65536 bf16
{
    int g = blockIdx.x * 256 + threadIdx.x;  // 0..8191
    int lane = g & 63;
    int ks = (g >> 6) & 7;
    int mt16 = g >> 9;
    int m = mt16 * 16 + (lane & 15);
    int o = m & 127;
    int modd = (m >= 128);
    unsigned short t8[8];
    #pragma unroll
    for (int j = 0; j < 8; ++j) {
        int k = ks * 32 + (lane >> 4) * 8 + j;
        int i = k & 127;
        int tap = modd ? (k < 128 ? 2 : 0) : (k < 128 ? 3 : 1);
        t8[j] = f32_to_bf16(w_ct[((size_t)i * DNOUT + o) * 4 + tap]);
    }
    *reinterpret_cast<uint4*>(Aws + (size_t)g * 8) = *reinterpret_cast<const uint4*>(t8);
}

// ---------------- Kernel A: fused sparse branch (reads ws kNN) ----------------
__global__ __launch_bounds__(256) void sparse_direct_kernel(
    const float* __restrict__ SF,            // [16][512][256]
    const float* __restrict__ w_sp,          // [256][512]
    const int2* __restrict__ idxws, const float2* __restrict__ wgtws,
    const float* __restrict__ b_sp, const float* __restrict__ gamma_sp,
    const float* __restrict__ beta_sp,
    float* __restrict__ out)                 // [16][256][512] f32
{
    int b = blockIdx.y;
    int n0 = blockIdx.x * 8;                 // grid.x = 64
    int tid = threadIdx.x;

    __shared__ float fs[SPIN][8];            // 16 KB
    __shared__ int2   sij[8];
    __shared__ float2 swt[8];

    if (tid < 8) {
        sij[tid] = idxws[b * NBEF + n0 + tid];
        swt[tid] = wgtws[b * NBEF + n0 + tid];
    }
    __syncthreads();

    for (int l = tid; l < SPIN * 8; l += 256) {
        int c = l >> 3, nn = l & 7;
        int2  ij = sij[nn];
        float2 w = swt[nn];
        const float* row = SF + ((size_t)b * SPIN + c) * NSTK;
        fs[c][nn] = w.x * row[ij.x] + w.y * row[ij.y];
    }
    __syncthreads();

    int o = tid;
    float acc[8] = {0,0,0,0,0,0,0,0};
    const float4* wr4 = reinterpret_cast<const float4*>(w_sp + (size_t)o * SPIN);
    #pragma unroll 4
    for (int c4 = 0; c4 < SPIN / 4; ++c4) {
        float4 a = wr4[c4];
        int c = c4 * 4;
        #pragma unroll
        for (int nn = 0; nn < 8; ++nn)
            acc[nn] += a.x * fs[c][nn] + a.y * fs[c+1][nn]
                     + a.z * fs[c+2][nn] + a.w * fs[c+3][nn];
    }

    const float invs = 1.0f / sqrtf(1.0f + 1e-5f);
    float bias  = b_sp[o];
    float scale = gamma_sp[o] * invs;
    float beta  = beta_sp[o];
    float r[8];
    #pragma unroll
    for (int q = 0; q < 8; ++q)
        r[q] = fast_gelu((acc[q] + bias) * scale + beta);
    float* dst = out + ((size_t)b * SPOUT + o) * NBEF + n0;
    *reinterpret_cast<float4*>(dst)     = make_float4(r[0], r[1], r[2], r[3]);
    *reinterpret_cast<float4*>(dst + 4) = make_float4(r[4], r[5], r[6], r[7]);
}

// ---------------- Kernel B: dense branch via bf16 MFMA (DMA-staged, A from ws) ----------------
// Staging v2: per stroke nl, the two gathered i-planes (128 i x 32 sp f32) are DMA'd into
// Y[2][128][32] by global_load_lds width=16 with PRE-SWIZZLED per-lane source (spq ^= i&7 at
// 16B granules; linear LDS dest = wave-uniform base + lane*16).  Phase 2 reads i-contiguous
// octets (conflict-free scalar b32: bank = (spq^(p&7))*4 + (sp&3)), interpolates, converts to
// bf16 and writes the swizzled col-major Xs fragment layout (unchanged).
__global__ __launch_bounds__(512) void dense_mfma_kernel(
    const float* __restrict__ DF,            // [16][128][256][32]
    const unsigned short* __restrict__ Aws,  // fragment-linear A, 128 KB
    const float* __restrict__ b_ct,
    const float* __restrict__ gamma_dn,
    const float* __restrict__ beta_dn,
    const int2* __restrict__ idxws, const float2* __restrict__ wgtws,
    float* __restrict__ outd)                // [16][128][32768] f32 (already offset)
{
    int blk = blockIdx.x;                    // 0..127 (4 strokes each)
    int b   = blockIdx.y;
    int n0  = blk * 4;
    int S0  = n0 * 32;
    int T0  = n0 * 64;
    int tid  = threadIdx.x;
    int lane = tid & 63;
    int wid  = tid >> 6;                     // 0..7
    int rit  = lane & 15;
    int kgrp = lane >> 4;                    // 0..3

    __shared__ float Y[2][128][32];          // 32 KB DMA landing buffer (swizzled slots)
    __shared__ unsigned short Xs[146 * 128]; // 37.4 KB
    __shared__ int2   sij[6];
    __shared__ float2 swt[6];
    __shared__ float bnb[128], bns[128], bnt[128];

    const float invs = 1.0f / sqrtf(1.0f + 1e-5f);
    if (tid < 128) {
        bnb[tid] = b_ct[tid];
        bns[tid] = gamma_dn[tid] * invs;
        bnt[tid] = beta_dn[tid];
    }
    if (tid < 6) {
        int s = n0 - 1 + tid;
        s = (s < 0) ? 0 : ((s > NBEF - 1) ? NBEF - 1 : s);
        sij[tid] = idxws[b * NBEF + s];
        swt[tid] = wgtws[b * NBEF + s];
    }
    // zero-fill pad cols 130..145
    if (tid < 256) {
        uint4 z = make_uint4(0, 0, 0, 0);
        *reinterpret_cast<uint4*>(&Xs[130 * 128 + tid * 8]) = z;
    }

    const float* DFb = DF + (size_t)b * (DNIN * NSTK * NPNT);

    // ---- halo cols 0 and 129 (scalar, tiny) ----
    __syncthreads();   // sij ready
    if (tid < 256) {
        int i    = tid & 127;
        int side = tid >> 7;
        int col  = side ? 129 : 0;
        int L    = side ? (S0 + 128) : (S0 - 1);
        L = (L < 0) ? 0 : ((L > 16383) ? 16383 : L);
        int stroke = L >> 5, pt = L & 31;
        int slot = stroke - (n0 - 1);
        int2  ij = sij[slot];
        float2 w = swt[slot];
        float v = w.x * DFb[(size_t)i * 8192 + (size_t)ij.x * NPNT + pt]
                + w.y * DFb[(size_t)i * 8192 + (size_t)ij.y * NPNT + pt];
        int dst = col * 128 + ((((i >> 3) ^ (col & 15))) << 3) + (i & 7);
        Xs[dst] = f32_to_bf16(v);
    }

    // ---- A fragments: coalesced 16B loads from fragment-linear ws ----
    bf16x8v afrag[2][8];
    #pragma unroll
    for (int mt = 0; mt < 2; ++mt) {
        int mt16 = wid + mt * 8;
        #pragma unroll
        for (int ks = 0; ks < 8; ++ks) {
            afrag[mt][ks] = *reinterpret_cast<const bf16x8v*>(
                Aws + (((size_t)(mt16 * 8 + ks)) * 64 + lane) * 8);
        }
    }

    // ---- staged interp: per stroke, DMA both neighbor planes then transpose+interp ----
    float* Yf = &Y[0][0][0];
    int swq = (lane & 7) ^ ((lane >> 3) & 7);        // pre-swizzled 16B-chunk index
    int sp2 = tid >> 4, oct = tid & 15;              // phase-2 slot: 32 sp x 16 octets
    #pragma unroll 1
    for (int nl = 0; nl < 4; ++nl) {
        int2 ij = sij[nl + 1];
        // phase 1: DMA (each wave: 2 i-groups x 2 neighbors = 4 instrs)
        #pragma unroll
        for (int q = 0; q < 2; ++q) {
            int i0 = wid * 16 + q * 8;
            int i  = i0 + (lane >> 3);
            const float* g0 = DFb + (size_t)i * 8192 + (size_t)ij.x * NPNT + (swq << 2);
            const float* g1 = DFb + (size_t)i * 8192 + (size_t)ij.y * NPNT + (swq << 2);
            __builtin_amdgcn_global_load_lds((gas1_t)(const void*)g0,
                (las3_t)(void*)&Y[0][i0][0], 16, 0, 0);
            __builtin_amdgcn_global_load_lds((gas1_t)(const void*)g1,
                (las3_t)(void*)&Y[1][i0][0], 16, 0, 0);
        }
        __syncthreads();                     // drains vmcnt (compiler-inserted) + barrier
        // phase 2: i-contiguous octet read + interp + bf16 pack -> Xs
        {
            float2 w = swt[nl + 1];
            int i0 = oct * 8;
            unsigned short t8[8];
            #pragma unroll
            for (int p = 0; p < 8; ++p) {
                int ip = i0 + p;
                int a = ip * 32 + (((sp2 >> 2) ^ (ip & 7)) << 2) + (sp2 & 3);
                float v = w.x * Yf[a] + w.y * Yf[4096 + a];
                t8[p] = f32_to_bf16(v);
            }
            int col = nl * 32 + sp2 + 1;
            int dst = col * 128 + ((oct ^ (col & 15)) << 3);
            *reinterpret_cast<uint4*>(&Xs[dst]) = *reinterpret_cast<const uint4*>(t8);
        }
        __syncthreads();                     // protect Y before next stroke's DMA
    }

    // ---- MFMA main loop: 9 N-tiles x 8 K-steps x 2 M-tiles ----
    #pragma unroll 1
    for (int nt = 0; nt < 9; ++nt) {
        f32x4v acc0 = {0.f, 0.f, 0.f, 0.f};
        f32x4v acc1 = {0.f, 0.f, 0.f, 0.f};
        #pragma unroll
        for (int ks = 0; ks < 8; ++ks) {
            int kb   = ks * 32 + kgrp * 8;
            int half = kb >> 7;
            int i    = kb & 127;
            int col  = nt * 16 + rit + half;
            int src  = col * 128 + ((((i >> 3) ^ (col & 15))) << 3);
            bf16x8v bfrag = *reinterpret_cast<const bf16x8v*>(&Xs[src]);
            acc0 = __builtin_amdgcn_mfma_f32_16x16x32_bf16(afrag[0][ks], bfrag, acc0, 0, 0, 0);
            acc1 = __builtin_amdgcn_mfma_f32_16x16x32_bf16(afrag[1][ks], bfrag, acc1, 0, 0, 0);
        }
        int c = nt * 16 + rit;               // C/D col = lane&15
        int srcl = (lane & 48) | ((lane + 1) & 15);
        #pragma unroll
        for (int q = 0; q < 4; ++q) {
            float a1n = __shfl(acc1[q], srcl, 64);   // C[o+128, c+1] (valid rit<15)
            int o = wid * 16 + kgrp * 4 + q;         // C/D row = (lane>>4)*4+q
            float bias = bnb[o], scale = bns[o], beta = bnt[o];
            size_t rowbase = (((size_t)b * DNOUT + o) << 15) + (size_t)T0;
            if (c < 128) {
                float ye = fast_gelu((acc0[q] + bias) * scale + beta);
                if (rit < 15) {
                    float yo = fast_gelu((a1n + bias) * scale + beta);
                    *reinterpret_cast<float2*>(outd + rowbase + 2 * c) = make_float2(ye, yo);
                } else {
                    outd[rowbase + 2 * c] = ye;
                }
            }
            if (rit == 0 && c >= 1) {
                float yo0 = fast_gelu((acc1[q] + bias) * scale + beta);
                outd[rowbase + 2 * c - 1] = yo0;
            }
        }
    }
}

extern "C" void kernel_launch(void* const* d_in, const int* in_sizes, int n_in,
                              void* d_out, int out_size, void* d_ws, size_t ws_size,
                              hipStream_t stream) {
    const float* sparse_fea   = (const float*)d_in[0];
    const float* dense_fea    = (const float*)d_in[1];
    const float* stk_coor     = (const float*)d_in[2];
    const float* stk_coor_bef = (const float*)d_in[3];
    const float* w_sp     = (const float*)d_in[4];
    const float* b_sp     = (const float*)d_in[5];
    const float* gamma_sp = (const float*)d_in[6];
    const float* beta_sp  = (const float*)d_in[7];
    const float* w_ct     = (const float*)d_in[8];
    const float* b_ct     = (const float*)d_in[9];
    const float* gamma_dn = (const float*)d_in[10];
    const float* beta_dn  = (const float*)d_in[11];
    float* out = (float*)d_out;

    char* ws = (char*)d_ws;
    int2*   idx = (int2*)ws;                          // 64 KB
    float2* wgt = (float2*)(ws + 65536);              // 64 KB
    unsigned short* Aws = (unsigned short*)(ws + 131072);  // 128 KB (total 256 KB)

    knn_kernel<<<dim3(NBEF / 16, NB), 256, 0, stream>>>(stk_coor, stk_coor_bef, idx, wgt);
    prep_a_kernel<<<32, 256, 0, stream>>>(w_ct, Aws);
    sparse_direct_kernel<<<dim3(NBEF / 8, NB), 256, 0, stream>>>(
        sparse_fea, w_sp, idx, wgt, b_sp, gamma_sp, beta_sp, out);
    dense_mfma_kernel<<<dim3(NBEF / 4, NB), 512, 0, stream>>>(
        dense_fea, Aws, b_ct, gamma_dn, beta_dn, idx, wgt, out + SP_ELEMS);
}

// Round 11
// 228.538 us; speedup vs baseline: 1.1645x; 1.1645x over previous
//
#include <hip/hip_runtime.h>
#include <math.h>

#define NB   16
#define NBEF 512
#define NSTK 256
#define CCO  128
#define SPIN 512
#define SPOUT 256
#define DNIN 128
#define DNOUT 128
#define NPNT 32
#define SP_ELEMS (NB * SPOUT * NBEF)   // 2,097,152 f32 elems (sparse output)

typedef __attribute__((ext_vector_type(8))) short bf16x8v;   // 8 bf16 = 4 VGPR
typedef __attribute__((ext_vector_type(4))) float f32x4v;    // MFMA C/D

typedef __attribute__((address_space(1))) const unsigned int* gas1_t;
typedef __attribute__((address_space(3))) unsigned int* las3_t;

__device__ __forceinline__ unsigned short f32_to_bf16(float f) {
    unsigned int u = __float_as_uint(f);
    u += 0x7fffu + ((u >> 16) & 1u);     // round-to-nearest-even
    return (unsigned short)(u >> 16);
}

// gelu(tanh approx) with hw exp2: tanh(z)=sign(z)*(1-2/(2^(2|z|*log2e)+1))
__device__ __forceinline__ float fast_gelu(float x) {
    float z = 0.7978845608028654f * x * (1.0f + 0.044715f * x * x);
    float az = fabsf(z) * 2.885390081777927f;   // 2*log2(e)
    float e;
    asm("v_exp_f32 %0, %1" : "=v"(e) : "v"(az));
    float r = __builtin_amdgcn_rcpf(e + 1.0f);
    float th = copysignf(1.0f - 2.0f * r, z);
    return 0.5f * x * (1.0f + th);
}

// order-preserving float -> uint map
__device__ __forceinline__ unsigned int f2ord(float f) {
    unsigned int u = __float_as_uint(f);
    return (u & 0x80000000u) ? ~u : (u | 0x80000000u);
}
__device__ __forceinline__ float ord2f(unsigned int o) {
    unsigned int u = (o & 0x80000000u) ? (o & 0x7fffffffu) : ~o;
    return __uint_as_float(u);
}

__device__ __forceinline__ unsigned long long wave_min_u64(unsigned long long k) {
    #pragma unroll
    for (int d = 32; d >= 1; d >>= 1) {
        unsigned long long o = __shfl_xor(k, d, 64);
        if (o < k) k = o;
    }
    return k;
}

// ---------------- Kernel 0: tiled 2-NN (GEMM-style staging, wave-local top-2) ----------------
__global__ __launch_bounds__(256) void knn_kernel(
    const float* __restrict__ stk_coor,      // [B][256][128]
    const float* __restrict__ stk_coor_bef,  // [B][512][128]
    int2* __restrict__ idx_out,              // [B][512]
    float2* __restrict__ w_out)              // [B][512]
{
    int b  = blockIdx.y;
    int q0 = blockIdx.x * 16;
    int tid  = threadIdx.x;
    int lane = tid & 63;
    int qg   = tid >> 6;                     // wave id: queries qg*4..+4
    int pg   = lane;                         // points pg*4..+4

    __shared__ float Qt[128][16];            // [c][q] 8 KB
    __shared__ float Pt[32][260];            // [c-chunk][p] 33.3 KB (pad 4)

    {
        int q = tid >> 4, c0 = (tid & 15) * 8;
        const float* src = stk_coor_bef + ((size_t)b * NBEF + q0 + q) * CCO + c0;
        float4 v0 = *reinterpret_cast<const float4*>(src);
        float4 v1 = *reinterpret_cast<const float4*>(src + 4);
        Qt[c0+0][q] = v0.x; Qt[c0+1][q] = v0.y; Qt[c0+2][q] = v0.z; Qt[c0+3][q] = v0.w;
        Qt[c0+4][q] = v1.x; Qt[c0+5][q] = v1.y; Qt[c0+6][q] = v1.z; Qt[c0+7][q] = v1.w;
    }

    float dot[4][4];
    #pragma unroll
    for (int a = 0; a < 4; ++a)
        #pragma unroll
        for (int c = 0; c < 4; ++c) dot[a][c] = 0.f;
    float qn[4] = {0.f, 0.f, 0.f, 0.f};
    float pn[4] = {0.f, 0.f, 0.f, 0.f};

    for (int ct = 0; ct < 4; ++ct) {
        __syncthreads();
        #pragma unroll
        for (int it = 0; it < 8; ++it) {
            int p  = (tid >> 3) + it * 32;
            int cl = (tid & 7) * 4;
            float4 v = *reinterpret_cast<const float4*>(
                stk_coor + ((size_t)b * NSTK + p) * CCO + ct * 32 + cl);
            Pt[cl+0][p] = v.x; Pt[cl+1][p] = v.y; Pt[cl+2][p] = v.z; Pt[cl+3][p] = v.w;
        }
        __syncthreads();
        #pragma unroll 8
        for (int c = 0; c < 32; ++c) {
            float4 qv = *reinterpret_cast<const float4*>(&Qt[ct*32 + c][qg*4]);
            float4 pv = *reinterpret_cast<const float4*>(&Pt[c][pg*4]);
            float qa[4] = {qv.x, qv.y, qv.z, qv.w};
            float pa[4] = {pv.x, pv.y, pv.z, pv.w};
            #pragma unroll
            for (int j = 0; j < 4; ++j) {
                qn[j] += qa[j] * qa[j];
                pn[j] += pa[j] * pa[j];
                #pragma unroll
                for (int k = 0; k < 4; ++k) dot[j][k] += qa[j] * pa[k];
            }
        }
    }

    #pragma unroll
    for (int qj = 0; qj < 4; ++qj) {
        unsigned long long kA = 0xFFFFFFFFFFFFFFFFull, kB = 0xFFFFFFFFFFFFFFFFull;
        #pragma unroll
        for (int pj = 0; pj < 4; ++pj) {
            float d2 = qn[qj] + pn[pj] - 2.f * dot[qj][pj];
            unsigned long long key =
                ((unsigned long long)f2ord(d2) << 32) | (unsigned int)(pg * 4 + pj);
            if (key < kA)      { kB = kA; kA = key; }
            else if (key < kB) { kB = key; }
        }
        unsigned long long m0 = wave_min_u64(kA);
        unsigned long long c2 = (kA == m0) ? kB : kA;
        unsigned long long m1 = wave_min_u64(c2);
        if (lane == 0) {
            float d0 = ord2f((unsigned int)(m0 >> 32));
            float d1 = ord2f((unsigned int)(m1 >> 32));
            int j0 = (int)(m0 & 0xffffffffu), j1 = (int)(m1 & 0xffffffffu);
            float r0 = 1.f / (d0 + 1e-8f);
            float r1 = 1.f / (d1 + 1e-8f);
            float s = r0 + r1;
            int q = q0 + qg * 4 + qj;
            idx_out[b * NBEF + q] = make_int2(j0, j1);
            w_out[b * NBEF + q]   = make_float2(r0 / s, r1 / s);
        }
    }
}

// ---------------- Kernel 1: one-time A-matrix -> MFMA-fragment-linear bf16 ----------------
__global__ __launch_bounds__(256) void prep_a_kernel(
    const float* __restrict__ w_ct,          // [128][128][4]
    unsigned short* __restrict__ Aws)        // 65536 bf16
{
    int g = blockIdx.x * 256 + threadIdx.x;  // 0..8191
    int lane = g & 63;
    int ks = (g >> 6) & 7;
    int mt16 = g >> 9;
    int m = mt16 * 16 + (lane & 15);
    int o = m & 127;
    int modd = (m >= 128);
    unsigned short t8[8];
    #pragma unroll
    for (int j = 0; j < 8; ++j) {
        int k = ks * 32 + (lane >> 4) * 8 + j;
        int i = k & 127;
        int tap = modd ? (k < 128 ? 2 : 0) : (k < 128 ? 3 : 1);
        t8[j] = f32_to_bf16(w_ct[((size_t)i * DNOUT + o) * 4 + tap]);
    }
    *reinterpret_cast<uint4*>(Aws + (size_t)g * 8) = *reinterpret_cast<const uint4*>(t8);
}

// ---------------- Kernel A: fused sparse branch (reads ws kNN) ----------------
__global__ __launch_bounds__(256) void sparse_direct_kernel(
    const float* __restrict__ SF,            // [16][512][256]
    const float* __restrict__ w_sp,          // [256][512]
    const int2* __restrict__ idxws, const float2* __restrict__ wgtws,
    const float* __restrict__ b_sp, const float* __restrict__ gamma_sp,
    const float* __restrict__ beta_sp,
    float* __restrict__ out)                 // [16][256][512] f32
{
    int b = blockIdx.y;
    int n0 = blockIdx.x * 8;                 // grid.x = 64
    int tid = threadIdx.x;

    __shared__ float fs[SPIN][8];            // 16 KB
    __shared__ int2   sij[8];
    __shared__ float2 swt[8];

    if (tid < 8) {
        sij[tid] = idxws[b * NBEF + n0 + tid];
        swt[tid] = wgtws[b * NBEF + n0 + tid];
    }
    __syncthreads();

    for (int l = tid; l < SPIN * 8; l += 256) {
        int c = l >> 3, nn = l & 7;
        int2  ij = sij[nn];
        float2 w = swt[nn];
        const float* row = SF + ((size_t)b * SPIN + c) * NSTK;
        fs[c][nn] = w.x * row[ij.x] + w.y * row[ij.y];
    }
    __syncthreads();

    int o = tid;
    float acc[8] = {0,0,0,0,0,0,0,0};
    const float4* wr4 = reinterpret_cast<const float4*>(w_sp + (size_t)o * SPIN);
    #pragma unroll 4
    for (int c4 = 0; c4 < SPIN / 4; ++c4) {
        float4 a = wr4[c4];
        int c = c4 * 4;
        #pragma unroll
        for (int nn = 0; nn < 8; ++nn)
            acc[nn] += a.x * fs[c][nn] + a.y * fs[c+1][nn]
                     + a.z * fs[c+2][nn] + a.w * fs[c+3][nn];
    }

    const float invs = 1.0f / sqrtf(1.0f + 1e-5f);
    float bias  = b_sp[o];
    float scale = gamma_sp[o] * invs;
    float beta  = beta_sp[o];
    float r[8];
    #pragma unroll
    for (int q = 0; q < 8; ++q)
        r[q] = fast_gelu((acc[q] + bias) * scale + beta);
    float* dst = out + ((size_t)b * SPOUT + o) * NBEF + n0;
    *reinterpret_cast<float4*>(dst)     = make_float4(r[0], r[1], r[2], r[3]);
    *reinterpret_cast<float4*>(dst + 4) = make_float4(r[4], r[5], r[6], r[7]);
}

// ---------------- Kernel B: dense branch via bf16 MFMA (DMA-staged, A from ws) ----------------
// Staging: per stroke nl, both gathered i-planes (128 i x 32 sp f32) are DMA'd into
// Y[2][128][32] via global_load_lds width=16 with pre-swizzled per-lane source (chunk ^= i&7;
// linear LDS dest = wave-uniform base + lane*16).  Phase 2 (FIXED lane map): lane l of wave w
// handles sp = l&31, oct = 2w + (l>>5); read bank = ((sp>>2)^(p&7))*4 + (sp&3) spans all 32
// banks across the wave (2 lanes/bank = conflict-free), then interp -> bf16 -> swizzled Xs.
__global__ __launch_bounds__(512) void dense_mfma_kernel(
    const float* __restrict__ DF,            // [16][128][256][32]
    const unsigned short* __restrict__ Aws,  // fragment-linear A, 128 KB
    const float* __restrict__ b_ct,
    const float* __restrict__ gamma_dn,
    const float* __restrict__ beta_dn,
    const int2* __restrict__ idxws, const float2* __restrict__ wgtws,
    float* __restrict__ outd)                // [16][128][32768] f32 (already offset)
{
    int blk = blockIdx.x;                    // 0..127 (4 strokes each)
    int b   = blockIdx.y;
    int n0  = blk * 4;
    int S0  = n0 * 32;
    int T0  = n0 * 64;
    int tid  = threadIdx.x;
    int lane = tid & 63;
    int wid  = tid >> 6;                     // 0..7
    int rit  = lane & 15;
    int kgrp = lane >> 4;                    // 0..3

    __shared__ float Y[2][128][32];          // 32 KB DMA landing buffer (swizzled slots)
    __shared__ unsigned short Xs[146 * 128]; // 37.4 KB
    __shared__ int2   sij[6];
    __shared__ float2 swt[6];
    __shared__ float bnb[128], bns[128], bnt[128];

    const float invs = 1.0f / sqrtf(1.0f + 1e-5f);
    if (tid < 128) {
        bnb[tid] = b_ct[tid];
        bns[tid] = gamma_dn[tid] * invs;
        bnt[tid] = beta_dn[tid];
    }
    if (tid < 6) {
        int s = n0 - 1 + tid;
        s = (s < 0) ? 0 : ((s > NBEF - 1) ? NBEF - 1 : s);
        sij[tid] = idxws[b * NBEF + s];
        swt[tid] = wgtws[b * NBEF + s];
    }
    // zero-fill pad cols 130..145
    if (tid < 256) {
        uint4 z = make_uint4(0, 0, 0, 0);
        *reinterpret_cast<uint4*>(&Xs[130 * 128 + tid * 8]) = z;
    }

    const float* DFb = DF + (size_t)b * (DNIN * NSTK * NPNT);

    // ---- halo cols 0 and 129 (scalar, tiny) ----
    __syncthreads();   // sij ready
    if (tid < 256) {
        int i    = tid & 127;
        int side = tid >> 7;
        int col  = side ? 129 : 0;
        int L    = side ? (S0 + 128) : (S0 - 1);
        L = (L < 0) ? 0 : ((L > 16383) ? 16383 : L);
        int stroke = L >> 5, pt = L & 31;
        int slot = stroke - (n0 - 1);
        int2  ij = sij[slot];
        float2 w = swt[slot];
        float v = w.x * DFb[(size_t)i * 8192 + (size_t)ij.x * NPNT + pt]
                + w.y * DFb[(size_t)i * 8192 + (size_t)ij.y * NPNT + pt];
        int dst = col * 128 + ((((i >> 3) ^ (col & 15))) << 3) + (i & 7);
        Xs[dst] = f32_to_bf16(v);
    }

    // ---- A fragments: coalesced 16B loads from fragment-linear ws ----
    bf16x8v afrag[2][8];
    #pragma unroll
    for (int mt = 0; mt < 2; ++mt) {
        int mt16 = wid + mt * 8;
        #pragma unroll
        for (int ks = 0; ks < 8; ++ks) {
            afrag[mt][ks] = *reinterpret_cast<const bf16x8v*>(
                Aws + (((size_t)(mt16 * 8 + ks)) * 64 + lane) * 8);
        }
    }

    // ---- staged interp: per stroke, DMA both neighbor planes then transpose+interp ----
    float* Yf = &Y[0][0][0];
    int swq = (lane & 7) ^ ((lane >> 3) & 7);        // pre-swizzled 16B-chunk index
    int sp2  = lane & 31;                            // FIXED: varies within wave
    int oct2 = wid * 2 + (lane >> 5);                // i-octet index 0..15
    #pragma unroll 1
    for (int nl = 0; nl < 4; ++nl) {
        int2 ij = sij[nl + 1];
        // phase 1: DMA (each wave: 2 i-groups x 2 neighbors = 4 instrs)
        #pragma unroll
        for (int q = 0; q < 2; ++q) {
            int i0 = wid * 16 + q * 8;
            int i  = i0 + (lane >> 3);
            const float* g0 = DFb + (size_t)i * 8192 + (size_t)ij.x * NPNT + (swq << 2);
            const float* g1 = DFb + (size_t)i * 8192 + (size_t)ij.y * NPNT + (swq << 2);
            __builtin_amdgcn_global_load_lds((gas1_t)(const void*)g0,
                (las3_t)(void*)&Y[0][i0][0], 16, 0, 0);
            __builtin_amdgcn_global_load_lds((gas1_t)(const void*)g1,
                (las3_t)(void*)&Y[1][i0][0], 16, 0, 0);
        }
        __syncthreads();                     // drains vmcnt + barrier
        // phase 2: i-contiguous octet read (conflict-free) + interp + bf16 pack -> Xs
        {
            float2 w = swt[nl + 1];
            int i0 = oct2 * 8;
            unsigned short t8[8];
            #pragma unroll
            for (int p = 0; p < 8; ++p) {
                int ip = i0 + p;
                int a = ip * 32 + (((sp2 >> 2) ^ (ip & 7)) << 2) + (sp2 & 3);
                float v = w.x * Yf[a] + w.y * Yf[4096 + a];
                t8[p] = f32_to_bf16(v);
            }
            int col = nl * 32 + sp2 + 1;
            int dst = col * 128 + ((oct2 ^ (col & 15)) << 3);
            *reinterpret_cast<uint4*>(&Xs[dst]) = *reinterpret_cast<const uint4*>(t8);
        }
        __syncthreads();                     // protect Y before next stroke's DMA
    }

    // ---- MFMA main loop: 9 N-tiles x 8 K-steps x 2 M-tiles ----
    #pragma unroll 1
    for (int nt = 0; nt < 9; ++nt) {
        f32x4v acc0 = {0.f, 0.f, 0.f, 0.f};
        f32x4v acc1 = {0.f, 0.f, 0.f, 0.f};
        #pragma unroll
        for (int ks = 0; ks < 8; ++ks) {
            int kb   = ks * 32 + kgrp * 8;
            int half = kb >> 7;
            int i    = kb & 127;
            int col  = nt * 16 + rit + half;
            int src  = col * 128 + ((((i >> 3) ^ (col & 15))) << 3);
            bf16x8v bfrag = *reinterpret_cast<const bf16x8v*>(&Xs[src]);
            acc0 = __builtin_amdgcn_mfma_f32_16x16x32_bf16(afrag[0][ks], bfrag, acc0, 0, 0, 0);
            acc1 = __builtin_amdgcn_mfma_f32_16x16x32_bf16(afrag[1][ks], bfrag, acc1, 0, 0, 0);
        }
        int c = nt * 16 + rit;               // C/D col = lane&15
        int srcl = (lane & 48) | ((lane + 1) & 15);
        #pragma unroll
        for (int q = 0; q < 4; ++q) {
            float a1n = __shfl(acc1[q], srcl, 64);   // C[o+128, c+1] (valid rit<15)
            int o = wid * 16 + kgrp * 4 + q;         // C/D row = (lane>>4)*4+q
            float bias = bnb[o], scale = bns[o], beta = bnt[o];
            size_t rowbase = (((size_t)b * DNOUT + o) << 15) + (size_t)T0;
            if (c < 128) {
                float ye = fast_gelu((acc0[q] + bias) * scale + beta);
                if (rit < 15) {
                    float yo = fast_gelu((a1n + bias) * scale + beta);
                    *reinterpret_cast<float2*>(outd + rowbase + 2 * c) = make_float2(ye, yo);
                } else {
                    outd[rowbase + 2 * c] = ye;
                }
            }
            if (rit == 0 && c >= 1) {
                float yo0 = fast_gelu((acc1[q] + bias) * scale + beta);
                outd[rowbase + 2 * c - 1] = yo0;
            }
        }
    }
}

extern "C" void kernel_launch(void* const* d_in, const int* in_sizes, int n_in,
                              void* d_out, int out_size, void* d_ws, size_t ws_size,
                              hipStream_t stream) {
    const float* sparse_fea   = (const float*)d_in[0];
    const float* dense_fea    = (const float*)d_in[1];
    const float* stk_coor     = (const float*)d_in[2];
    const float* stk_coor_bef = (const float*)d_in[3];
    const float* w_sp     = (const float*)d_in[4];
    const float* b_sp     = (const float*)d_in[5];
    const float* gamma_sp = (const float*)d_in[6];
    const float* beta_sp  = (const float*)d_in[7];
    const float* w_ct     = (const float*)d_in[8];
    const float* b_ct     = (const float*)d_in[9];
    const float* gamma_dn = (const float*)d_in[10];
    const float* beta_dn  = (const float*)d_in[11];
    float* out = (float*)d_out;

    char* ws = (char*)d_ws;
    int2*   idx = (int2*)ws;                          // 64 KB
    float2* wgt = (float2*)(ws + 65536);              // 64 KB
    unsigned short* Aws = (unsigned short*)(ws + 131072);  // 128 KB (total 256 KB)

    knn_kernel<<<dim3(NBEF / 16, NB), 256, 0, stream>>>(stk_coor, stk_coor_bef, idx, wgt);
    prep_a_kernel<<<32, 256, 0, stream>>>(w_ct, Aws);
    sparse_direct_kernel<<<dim3(NBEF / 8, NB), 256, 0, stream>>>(
        sparse_fea, w_sp, idx, wgt, b_sp, gamma_sp, beta_sp, out);
    dense_mfma_kernel<<<dim3(NBEF / 4, NB), 512, 0, stream>>>(
        dense_fea, Aws, b_ct, gamma_dn, beta_dn, idx, wgt, out + SP_ELEMS);
}

// Round 12
// 218.557 us; speedup vs baseline: 1.2177x; 1.0457x over previous
//
#include <hip/hip_runtime.h>
#include <math.h>

#define NB   16
#define NBEF 512
#define NSTK 256
#define CCO  128
#define SPIN 512
#define SPOUT 256
#define DNIN 128
#define DNOUT 128
#define NPNT 32
#define SP_ELEMS (NB * SPOUT * NBEF)   // 2,097,152 f32 elems (sparse output)

typedef __attribute__((ext_vector_type(8))) short bf16x8v;   // 8 bf16 = 4 VGPR
typedef __attribute__((ext_vector_type(4))) float f32x4v;    // MFMA C/D

typedef __attribute__((address_space(1))) const unsigned int* gas1_t;
typedef __attribute__((address_space(3))) unsigned int* las3_t;

__device__ __forceinline__ unsigned short f32_to_bf16(float f) {
    unsigned int u = __float_as_uint(f);
    u += 0x7fffu + ((u >> 16) & 1u);     // round-to-nearest-even
    return (unsigned short)(u >> 16);
}

// gelu(tanh approx) with hw exp2: tanh(z)=sign(z)*(1-2/(2^(2|z|*log2e)+1))
__device__ __forceinline__ float fast_gelu(float x) {
    float z = 0.7978845608028654f * x * (1.0f + 0.044715f * x * x);
    float az = fabsf(z) * 2.885390081777927f;   // 2*log2(e)
    float e;
    asm("v_exp_f32 %0, %1" : "=v"(e) : "v"(az));
    float r = __builtin_amdgcn_rcpf(e + 1.0f);
    float th = copysignf(1.0f - 2.0f * r, z);
    return 0.5f * x * (1.0f + th);
}

// order-preserving float -> uint map
__device__ __forceinline__ unsigned int f2ord(float f) {
    unsigned int u = __float_as_uint(f);
    return (u & 0x80000000u) ? ~u : (u | 0x80000000u);
}
__device__ __forceinline__ float ord2f(unsigned int o) {
    unsigned int u = (o & 0x80000000u) ? (o & 0x7fffffffu) : ~o;
    return __uint_as_float(u);
}

__device__ __forceinline__ unsigned long long wave_min_u64(unsigned long long k) {
    #pragma unroll
    for (int d = 32; d >= 1; d >>= 1) {
        unsigned long long o = __shfl_xor(k, d, 64);
        if (o < k) k = o;
    }
    return k;
}

// ---------------- Kernel 0: tiled 2-NN (GEMM-style staging, wave-local top-2) ----------------
__global__ __launch_bounds__(256) void knn_kernel(
    const float* __restrict__ stk_coor,      // [B][256][128]
    const float* __restrict__ stk_coor_bef,  // [B][512][128]
    int2* __restrict__ idx_out,              // [B][512]
    float2* __restrict__ w_out)              // [B][512]
{
    int b  = blockIdx.y;
    int q0 = blockIdx.x * 16;
    int tid  = threadIdx.x;
    int lane = tid & 63;
    int qg   = tid >> 6;                     // wave id: queries qg*4..+4
    int pg   = lane;                         // points pg*4..+4

    __shared__ float Qt[128][16];            // [c][q] 8 KB
    __shared__ float Pt[32][260];            // [c-chunk][p] 33.3 KB (pad 4)

    {
        int q = tid >> 4, c0 = (tid & 15) * 8;
        const float* src = stk_coor_bef + ((size_t)b * NBEF + q0 + q) * CCO + c0;
        float4 v0 = *reinterpret_cast<const float4*>(src);
        float4 v1 = *reinterpret_cast<const float4*>(src + 4);
        Qt[c0+0][q] = v0.x; Qt[c0+1][q] = v0.y; Qt[c0+2][q] = v0.z; Qt[c0+3][q] = v0.w;
        Qt[c0+4][q] = v1.x; Qt[c0+5][q] = v1.y; Qt[c0+6][q] = v1.z; Qt[c0+7][q] = v1.w;
    }

    float dot[4][4];
    #pragma unroll
    for (int a = 0; a < 4; ++a)
        #pragma unroll
        for (int c = 0; c < 4; ++c) dot[a][c] = 0.f;
    float qn[4] = {0.f, 0.f, 0.f, 0.f};
    float pn[4] = {0.f, 0.f, 0.f, 0.f};

    for (int ct = 0; ct < 4; ++ct) {
        __syncthreads();
        #pragma unroll
        for (int it = 0; it < 8; ++it) {
            int p  = (tid >> 3) + it * 32;
            int cl = (tid & 7) * 4;
            float4 v = *reinterpret_cast<const float4*>(
                stk_coor + ((size_t)b * NSTK + p) * CCO + ct * 32 + cl);
            Pt[cl+0][p] = v.x; Pt[cl+1][p] = v.y; Pt[cl+2][p] = v.z; Pt[cl+3][p] = v.w;
        }
        __syncthreads();
        #pragma unroll 8
        for (int c = 0; c < 32; ++c) {
            float4 qv = *reinterpret_cast<const float4*>(&Qt[ct*32 + c][qg*4]);
            float4 pv = *reinterpret_cast<const float4*>(&Pt[c][pg*4]);
            float qa[4] = {qv.x, qv.y, qv.z, qv.w};
            float pa[4] = {pv.x, pv.y, pv.z, pv.w};
            #pragma unroll
            for (int j = 0; j < 4; ++j) {
                qn[j] += qa[j] * qa[j];
                pn[j] += pa[j] * pa[j];
                #pragma unroll
                for (int k = 0; k < 4; ++k) dot[j][k] += qa[j] * pa[k];
            }
        }
    }

    #pragma unroll
    for (int qj = 0; qj < 4; ++qj) {
        unsigned long long kA = 0xFFFFFFFFFFFFFFFFull, kB = 0xFFFFFFFFFFFFFFFFull;
        #pragma unroll
        for (int pj = 0; pj < 4; ++pj) {
            float d2 = qn[qj] + pn[pj] - 2.f * dot[qj][pj];
            unsigned long long key =
                ((unsigned long long)f2ord(d2) << 32) | (unsigned int)(pg * 4 + pj);
            if (key < kA)      { kB = kA; kA = key; }
            else if (key < kB) { kB = key; }
        }
        unsigned long long m0 = wave_min_u64(kA);
        unsigned long long c2 = (kA == m0) ? kB : kA;
        unsigned long long m1 = wave_min_u64(c2);
        if (lane == 0) {
            float d0 = ord2f((unsigned int)(m0 >> 32));
            float d1 = ord2f((unsigned int)(m1 >> 32));
            int j0 = (int)(m0 & 0xffffffffu), j1 = (int)(m1 & 0xffffffffu);
            float r0 = 1.f / (d0 + 1e-8f);
            float r1 = 1.f / (d1 + 1e-8f);
            float s = r0 + r1;
            int q = q0 + qg * 4 + qj;
            idx_out[b * NBEF + q] = make_int2(j0, j1);
            w_out[b * NBEF + q]   = make_float2(r0 / s, r1 / s);
        }
    }
}

// ---------------- Kernel 1: one-time A-matrix -> MFMA-fragment-linear bf16 ----------------
__global__ __launch_bounds__(256) void prep_a_kernel(
    const float* __restrict__ w_ct,          // [128][128][4]
    unsigned short* __restrict__ Aws)        // 65536 bf16
{
    int g = blockIdx.x * 256 + threadIdx.x;  // 0..8191
    int lane = g & 63;
    int ks = (g >> 6) & 7;
    int mt16 = g >> 9;
    int m = mt16 * 16 + (lane & 15);
    int o = m & 127;
    int modd = (m >= 128);
    unsigned short t8[8];
    #pragma unroll
    for (int j = 0; j < 8; ++j) {
        int k = ks * 32 + (lane >> 4) * 8 + j;
        int i = k & 127;
        int tap = modd ? (k < 128 ? 2 : 0) : (k < 128 ? 3 : 1);
        t8[j] = f32_to_bf16(w_ct[((size_t)i * DNOUT + o) * 4 + tap]);
    }
    *reinterpret_cast<uint4*>(Aws + (size_t)g * 8) = *reinterpret_cast<const uint4*>(t8);
}

// ---------------- Kernel 2: one-time w_sp quad-transpose -> wTq[c4][o] float4 ----------------
// wTq[c4][o] = w_sp[o][4*c4 .. 4*c4+3]; sparse inner loop then loads it lane-contiguously.
__global__ __launch_bounds__(256) void prep_wt_kernel(
    const float* __restrict__ w_sp,          // [256][512]
    float4* __restrict__ wTq)                // [128][256]
{
    int c4 = blockIdx.x;                     // 0..127
    int o  = threadIdx.x;                    // 0..255
    float4 v = *reinterpret_cast<const float4*>(w_sp + (size_t)o * SPIN + c4 * 4);
    wTq[c4 * 256 + o] = v;
}

// ---------------- Kernel A: fused sparse branch (reads ws kNN) ----------------
__global__ __launch_bounds__(256) void sparse_direct_kernel(
    const float* __restrict__ SF,            // [16][512][256]
    const float* __restrict__ w_sp,          // [256][512] (fallback path)
    const float4* __restrict__ wTq,          // [128][256] transposed weights (or null)
    const int2* __restrict__ idxws, const float2* __restrict__ wgtws,
    const float* __restrict__ b_sp, const float* __restrict__ gamma_sp,
    const float* __restrict__ beta_sp,
    float* __restrict__ out)                 // [16][256][512] f32
{
    int b = blockIdx.y;
    int n0 = blockIdx.x * 8;                 // grid.x = 64
    int tid = threadIdx.x;

    __shared__ float fs[SPIN][8];            // 16 KB
    __shared__ int2   sij[8];
    __shared__ float2 swt[8];

    if (tid < 8) {
        sij[tid] = idxws[b * NBEF + n0 + tid];
        swt[tid] = wgtws[b * NBEF + n0 + tid];
    }
    __syncthreads();

    for (int l = tid; l < SPIN * 8; l += 256) {
        int c = l >> 3, nn = l & 7;
        int2  ij = sij[nn];
        float2 w = swt[nn];
        const float* row = SF + ((size_t)b * SPIN + c) * NSTK;
        fs[c][nn] = w.x * row[ij.x] + w.y * row[ij.y];
    }
    __syncthreads();

    int o = tid;
    float acc[8] = {0,0,0,0,0,0,0,0};
    if (wTq) {
        // coalesced: lanes read consecutive o at fixed c4 (1 KB/wave-instr)
        #pragma unroll 4
        for (int c4 = 0; c4 < SPIN / 4; ++c4) {
            float4 a = wTq[c4 * 256 + o];
            int c = c4 * 4;
            #pragma unroll
            for (int nn = 0; nn < 8; ++nn)
                acc[nn] += a.x * fs[c][nn] + a.y * fs[c+1][nn]
                         + a.z * fs[c+2][nn] + a.w * fs[c+3][nn];
        }
    } else {
        const float4* wr4 = reinterpret_cast<const float4*>(w_sp + (size_t)o * SPIN);
        #pragma unroll 4
        for (int c4 = 0; c4 < SPIN / 4; ++c4) {
            float4 a = wr4[c4];
            int c = c4 * 4;
            #pragma unroll
            for (int nn = 0; nn < 8; ++nn)
                acc[nn] += a.x * fs[c][nn] + a.y * fs[c+1][nn]
                         + a.z * fs[c+2][nn] + a.w * fs[c+3][nn];
        }
    }

    const float invs = 1.0f / sqrtf(1.0f + 1e-5f);
    float bias  = b_sp[o];
    float scale = gamma_sp[o] * invs;
    float beta  = beta_sp[o];
    float r[8];
    #pragma unroll
    for (int q = 0; q < 8; ++q)
        r[q] = fast_gelu((acc[q] + bias) * scale + beta);
    float* dst = out + ((size_t)b * SPOUT + o) * NBEF + n0;
    *reinterpret_cast<float4*>(dst)     = make_float4(r[0], r[1], r[2], r[3]);
    *reinterpret_cast<float4*>(dst + 4) = make_float4(r[4], r[5], r[6], r[7]);
}

// ---------------- Kernel B: dense branch via bf16 MFMA (DMA-staged, A from ws) ----------------
// Staging: per stroke nl, both gathered i-planes (128 i x 32 sp f32) are DMA'd into
// Y[2][128][32] via global_load_lds width=16 with pre-swizzled per-lane source (chunk ^= i&7;
// linear LDS dest = wave-uniform base + lane*16).  Phase 2: lane l of wave w handles
// sp = l&31, oct = 2w + (l>>5); read bank = ((sp>>2)^(p&7))*4 + (sp&3) spans all 32 banks
// (2 lanes/bank = conflict-free), then interp -> bf16 -> swizzled Xs.
__global__ __launch_bounds__(512) void dense_mfma_kernel(
    const float* __restrict__ DF,            // [16][128][256][32]
    const unsigned short* __restrict__ Aws,  // fragment-linear A, 128 KB
    const float* __restrict__ b_ct,
    const float* __restrict__ gamma_dn,
    const float* __restrict__ beta_dn,
    const int2* __restrict__ idxws, const float2* __restrict__ wgtws,
    float* __restrict__ outd)                // [16][128][32768] f32 (already offset)
{
    int blk = blockIdx.x;                    // 0..127 (4 strokes each)
    int b   = blockIdx.y;
    int n0  = blk * 4;
    int S0  = n0 * 32;
    int T0  = n0 * 64;
    int tid  = threadIdx.x;
    int lane = tid & 63;
    int wid  = tid >> 6;                     // 0..7
    int rit  = lane & 15;
    int kgrp = lane >> 4;                    // 0..3

    __shared__ float Y[2][128][32];          // 32 KB DMA landing buffer (swizzled slots)
    __shared__ unsigned short Xs[146 * 128]; // 37.4 KB
    __shared__ int2   sij[6];
    __shared__ float2 swt[6];
    __shared__ float bnb[128], bns[128], bnt[128];

    const float invs = 1.0f / sqrtf(1.0f + 1e-5f);
    if (tid < 128) {
        bnb[tid] = b_ct[tid];
        bns[tid] = gamma_dn[tid] * invs;
        bnt[tid] = beta_dn[tid];
    }
    if (tid < 6) {
        int s = n0 - 1 + tid;
        s = (s < 0) ? 0 : ((s > NBEF - 1) ? NBEF - 1 : s);
        sij[tid] = idxws[b * NBEF + s];
        swt[tid] = wgtws[b * NBEF + s];
    }
    // zero-fill pad cols 130..145
    if (tid < 256) {
        uint4 z = make_uint4(0, 0, 0, 0);
        *reinterpret_cast<uint4*>(&Xs[130 * 128 + tid * 8]) = z;
    }

    const float* DFb = DF + (size_t)b * (DNIN * NSTK * NPNT);

    // ---- halo cols 0 and 129 (scalar, tiny) ----
    __syncthreads();   // sij ready
    if (tid < 256) {
        int i    = tid & 127;
        int side = tid >> 7;
        int col  = side ? 129 : 0;
        int L    = side ? (S0 + 128) : (S0 - 1);
        L = (L < 0) ? 0 : ((L > 16383) ? 16383 : L);
        int stroke = L >> 5, pt = L & 31;
        int slot = stroke - (n0 - 1);
        int2  ij = sij[slot];
        float2 w = swt[slot];
        float v = w.x * DFb[(size_t)i * 8192 + (size_t)ij.x * NPNT + pt]
                + w.y * DFb[(size_t)i * 8192 + (size_t)ij.y * NPNT + pt];
        int dst = col * 128 + ((((i >> 3) ^ (col & 15))) << 3) + (i & 7);
        Xs[dst] = f32_to_bf16(v);
    }

    // ---- A fragments: coalesced 16B loads from fragment-linear ws ----
    bf16x8v afrag[2][8];
    #pragma unroll
    for (int mt = 0; mt < 2; ++mt) {
        int mt16 = wid + mt * 8;
        #pragma unroll
        for (int ks = 0; ks < 8; ++ks) {
            afrag[mt][ks] = *reinterpret_cast<const bf16x8v*>(
                Aws + (((size_t)(mt16 * 8 + ks)) * 64 + lane) * 8);
        }
    }

    // ---- staged interp: per stroke, DMA both neighbor planes then transpose+interp ----
    float* Yf = &Y[0][0][0];
    int swq = (lane & 7) ^ ((lane >> 3) & 7);        // pre-swizzled 16B-chunk index
    int sp2  = lane & 31;                            // varies within wave
    int oct2 = wid * 2 + (lane >> 5);                // i-octet index 0..15
    #pragma unroll 1
    for (int nl = 0; nl < 4; ++nl) {
        int2 ij = sij[nl + 1];
        // phase 1: DMA (each wave: 2 i-groups x 2 neighbors = 4 instrs)
        #pragma unroll
        for (int q = 0; q < 2; ++q) {
            int i0 = wid * 16 + q * 8;
            int i  = i0 + (lane >> 3);
            const float* g0 = DFb + (size_t)i * 8192 + (size_t)ij.x * NPNT + (swq << 2);
            const float* g1 = DFb + (size_t)i * 8192 + (size_t)ij.y * NPNT + (swq << 2);
            __builtin_amdgcn_global_load_lds((gas1_t)(const void*)g0,
                (las3_t)(void*)&Y[0][i0][0], 16, 0, 0);
            __builtin_amdgcn_global_load_lds((gas1_t)(const void*)g1,
                (las3_t)(void*)&Y[1][i0][0], 16, 0, 0);
        }
        __syncthreads();                     // drains vmcnt + barrier
        // phase 2: i-contiguous octet read (conflict-free) + interp + bf16 pack -> Xs
        {
            float2 w = swt[nl + 1];
            int i0 = oct2 * 8;
            unsigned short t8[8];
            #pragma unroll
            for (int p = 0; p < 8; ++p) {
                int ip = i0 + p;
                int a = ip * 32 + (((sp2 >> 2) ^ (ip & 7)) << 2) + (sp2 & 3);
                float v = w.x * Yf[a] + w.y * Yf[4096 + a];
                t8[p] = f32_to_bf16(v);
            }
            int col = nl * 32 + sp2 + 1;
            int dst = col * 128 + ((oct2 ^ (col & 15)) << 3);
            *reinterpret_cast<uint4*>(&Xs[dst]) = *reinterpret_cast<const uint4*>(t8);
        }
        __syncthreads();                     // protect Y before next stroke's DMA
    }

    // ---- MFMA main loop: 9 N-tiles x 8 K-steps x 2 M-tiles ----
    #pragma unroll 1
    for (int nt = 0; nt < 9; ++nt) {
        f32x4v acc0 = {0.f, 0.f, 0.f, 0.f};
        f32x4v acc1 = {0.f, 0.f, 0.f, 0.f};
        #pragma unroll
        for (int ks = 0; ks < 8; ++ks) {
            int kb   = ks * 32 + kgrp * 8;
            int half = kb >> 7;
            int i    = kb & 127;
            int col  = nt * 16 + rit + half;
            int src  = col * 128 + ((((i >> 3) ^ (col & 15))) << 3);
            bf16x8v bfrag = *reinterpret_cast<const bf16x8v*>(&Xs[src]);
            acc0 = __builtin_amdgcn_mfma_f32_16x16x32_bf16(afrag[0][ks], bfrag, acc0, 0, 0, 0);
            acc1 = __builtin_amdgcn_mfma_f32_16x16x32_bf16(afrag[1][ks], bfrag, acc1, 0, 0, 0);
        }
        int c = nt * 16 + rit;               // C/D col = lane&15
        int srcl = (lane & 48) | ((lane + 1) & 15);
        #pragma unroll
        for (int q = 0; q < 4; ++q) {
            float a1n = __shfl(acc1[q], srcl, 64);   // C[o+128, c+1] (valid rit<15)
            int o = wid * 16 + kgrp * 4 + q;         // C/D row = (lane>>4)*4+q
            float bias = bnb[o], scale = bns[o], beta = bnt[o];
            size_t rowbase = (((size_t)b * DNOUT + o) << 15) + (size_t)T0;
            if (c < 128) {
                float ye = fast_gelu((acc0[q] + bias) * scale + beta);
                if (rit < 15) {
                    float yo = fast_gelu((a1n + bias) * scale + beta);
                    *reinterpret_cast<float2*>(outd + rowbase + 2 * c) = make_float2(ye, yo);
                } else {
                    outd[rowbase + 2 * c] = ye;
                }
            }
            if (rit == 0 && c >= 1) {
                float yo0 = fast_gelu((acc1[q] + bias) * scale + beta);
                outd[rowbase + 2 * c - 1] = yo0;
            }
        }
    }
}

extern "C" void kernel_launch(void* const* d_in, const int* in_sizes, int n_in,
                              void* d_out, int out_size, void* d_ws, size_t ws_size,
                              hipStream_t stream) {
    const float* sparse_fea   = (const float*)d_in[0];
    const float* dense_fea    = (const float*)d_in[1];
    const float* stk_coor     = (const float*)d_in[2];
    const float* stk_coor_bef = (const float*)d_in[3];
    const float* w_sp     = (const float*)d_in[4];
    const float* b_sp     = (const float*)d_in[5];
    const float* gamma_sp = (const float*)d_in[6];
    const float* beta_sp  = (const float*)d_in[7];
    const float* w_ct     = (const float*)d_in[8];
    const float* b_ct     = (const float*)d_in[9];
    const float* gamma_dn = (const float*)d_in[10];
    const float* beta_dn  = (const float*)d_in[11];
    float* out = (float*)d_out;

    char* ws = (char*)d_ws;
    int2*   idx = (int2*)ws;                               // 64 KB
    float2* wgt = (float2*)(ws + 65536);                   // 64 KB
    unsigned short* Aws = (unsigned short*)(ws + 131072);  // 128 KB
    bool use_wt = (ws_size >= 786432);                     // + 512 KB wTq = 768 KB total
    float4* wTq = use_wt ? (float4*)(ws + 262144) : nullptr;

    knn_kernel<<<dim3(NBEF / 16, NB), 256, 0, stream>>>(stk_coor, stk_coor_bef, idx, wgt);
    prep_a_kernel<<<32, 256, 0, stream>>>(w_ct, Aws);
    if (use_wt) prep_wt_kernel<<<128, 256, 0, stream>>>(w_sp, wTq);
    sparse_direct_kernel<<<dim3(NBEF / 8, NB), 256, 0, stream>>>(
        sparse_fea, w_sp, wTq, idx, wgt, b_sp, gamma_sp, beta_sp, out);
    dense_mfma_kernel<<<dim3(NBEF / 4, NB), 512, 0, stream>>>(
        dense_fea, Aws, b_ct, gamma_dn, beta_dn, idx, wgt, out + SP_ELEMS);
}